// Round 6
// baseline (2137.626 us; speedup 1.0000x reference)
//
#include <hip/hip_runtime.h>
#include <hip/hip_bf16.h>

#define N_NODES 100000
#define N_EDGES 300000
#define IN_DIM 10
#define HID 384
#define OUT_DIM 3
#define T_LAYERS 5
#define BN_EPS 1e-5f

typedef __attribute__((ext_vector_type(8))) short short8;
typedef __attribute__((ext_vector_type(4))) float floatx4;

__device__ __forceinline__ float bf16f(short v) {
  return __uint_as_float(((unsigned)(unsigned short)v) << 16);
}

// ------------------------- CSR build -------------------------

__global__ void count_k(const int* __restrict__ dst, int* __restrict__ cnt, int E) {
  int e = blockIdx.x * blockDim.x + threadIdx.x;
  if (e < E) atomicAdd(&cnt[dst[e]], 1);
}

__global__ void scan_partial_k(const int* __restrict__ cnt, int* __restrict__ bsum, int n) {
  int t = threadIdx.x;
  int i = blockIdx.x * 1024 + t;
  int v = (i < n) ? cnt[i] : 0;
  #pragma unroll
  for (int off = 1; off < 64; off <<= 1) v += __shfl_xor(v, off);
  __shared__ int ws[16];
  if ((t & 63) == 0) ws[t >> 6] = v;
  __syncthreads();
  if (t == 0) {
    int s = 0;
    #pragma unroll
    for (int w = 0; w < 16; ++w) s += ws[w];
    bsum[blockIdx.x] = s;
  }
}

__global__ void scan_small_k(int* __restrict__ bsum, int P) {
  __shared__ int s[1024];
  int t = threadIdx.x;
  int v = (t < P) ? bsum[t] : 0;
  s[t] = v;
  __syncthreads();
  for (int off = 1; off < 1024; off <<= 1) {
    int add = (t >= off) ? s[t - off] : 0;
    __syncthreads();
    s[t] += add;
    __syncthreads();
  }
  if (t < P) bsum[t] = s[t] - v;  // exclusive block-prefix
}

__global__ void scan_final_k(const int* __restrict__ cnt, const int* __restrict__ bsum,
                             int* __restrict__ row_off, int n) {
  int t = threadIdx.x, lane = t & 63, wv = t >> 6;
  int i = blockIdx.x * 1024 + t;
  int v = (i < n) ? cnt[i] : 0;
  int x = v;
  #pragma unroll
  for (int off = 1; off < 64; off <<= 1) {
    int y = __shfl_up(x, off);
    if (lane >= off) x += y;
  }
  __shared__ int ws[16];
  if (lane == 63) ws[wv] = x;
  __syncthreads();
  if (t == 0) {
    int a = 0;
    #pragma unroll
    for (int w = 0; w < 16; ++w) { int tmp = ws[w]; ws[w] = a; a += tmp; }
  }
  __syncthreads();
  int excl = (x - v) + ws[wv] + bsum[blockIdx.x];
  if (i <= n) row_off[i] = excl;
}

__global__ void fill_k(const int* __restrict__ src, const int* __restrict__ dst,
                       const int* __restrict__ row_off, int* __restrict__ cursor,
                       int* __restrict__ csr, int E) {
  int e = blockIdx.x * blockDim.x + threadIdx.x;
  if (e < E) {
    int d = dst[e];
    int pos = atomicAdd(&cursor[d], 1);
    csr[row_off[d] + pos] = src[e];
  }
}

// ------------------------- prepack kernels -------------------------

__global__ void conv_k(const float* __restrict__ src, __hip_bfloat16* __restrict__ dst, int n) {
  int i = blockIdx.x * blockDim.x + threadIdx.x;
  if (i < n) dst[i] = __float2bfloat16(src[i]);
}

// X2[n][64] = { x[n][0..10) , agg10[n][0..10) , 0 pad }
__global__ void pack0_k(const float* __restrict__ x, const float* __restrict__ agg10,
                        __hip_bfloat16* __restrict__ X2, int n) {
  int i = blockIdx.x * blockDim.x + threadIdx.x;
  if (i < n * 64) {
    int node = i >> 6, k = i & 63;
    float v = (k < IN_DIM) ? x[node * IN_DIM + k]
              : (k < 2 * IN_DIM) ? agg10[node * IN_DIM + (k - IN_DIM)] : 0.f;
    X2[i] = __float2bfloat16(v);
  }
}

// W2[o][64] = { W_r0 (pairs x) , W_l0 (pairs agg10) , 0 pad }
__global__ void packw0_k(const float* __restrict__ Wl, const float* __restrict__ Wr,
                         __hip_bfloat16* __restrict__ W2) {
  int i = blockIdx.x * blockDim.x + threadIdx.x;
  if (i < HID * 64) {
    int o = i >> 6, k = i & 63;
    float v = (k < IN_DIM) ? Wr[o * IN_DIM + k]
              : (k < 2 * IN_DIM) ? Wl[o * IN_DIM + (k - IN_DIM)]
              : 0.f;
    W2[i] = __float2bfloat16(v);
  }
}

// ------------------------- aggregation -------------------------

__global__ void agg10_k(const float* __restrict__ x, const int* __restrict__ row_off,
                        const int* __restrict__ csr, float* __restrict__ agg10, int n) {
  int sub = threadIdx.x >> 5;
  int lane = threadIdx.x & 31;
  int node = blockIdx.x * 8 + sub;
  if (node >= n) return;
  int s = row_off[node], e = row_off[node + 1];
  if (lane < IN_DIM) {
    float acc = 0.f;
    for (int j = s; j < e; ++j) acc += x[csr[j] * IN_DIM + lane];
    float c = (float)max(e - s, 1);
    agg10[node * IN_DIM + lane] = acc / c;
  }
}

// F=384 mean aggregation: one wave per node, lanes 0..47 hold 8 bf16 cols each.
__global__ __launch_bounds__(256) void aggv_k(const __hip_bfloat16* __restrict__ h,
                                              const int* __restrict__ row_off,
                                              const int* __restrict__ csr,
                                              __hip_bfloat16* __restrict__ agg, int n) {
  int node = blockIdx.x * 4 + (threadIdx.x >> 6);
  if (node >= n) return;
  int lane = threadIdx.x & 63;
  if (lane >= 48) return;
  int s = row_off[node], e = row_off[node + 1];
  float acc[8] = {0.f, 0.f, 0.f, 0.f, 0.f, 0.f, 0.f, 0.f};
  for (int j = s; j < e; ++j) {
    const uint4 v = *(const uint4*)(h + (size_t)csr[j] * HID + lane * 8);
    uint u0 = v.x, u1 = v.y, u2 = v.z, u3 = v.w;
    acc[0] += __uint_as_float(u0 << 16);
    acc[1] += __uint_as_float(u0 & 0xffff0000u);
    acc[2] += __uint_as_float(u1 << 16);
    acc[3] += __uint_as_float(u1 & 0xffff0000u);
    acc[4] += __uint_as_float(u2 << 16);
    acc[5] += __uint_as_float(u2 & 0xffff0000u);
    acc[6] += __uint_as_float(u3 << 16);
    acc[7] += __uint_as_float(u3 & 0xffff0000u);
  }
  float invc = 1.f / (float)max(e - s, 1);
  uint out[4];
  #pragma unroll
  for (int q = 0; q < 4; ++q) {
    __hip_bfloat16 lo = __float2bfloat16(acc[2 * q] * invc);
    __hip_bfloat16 hi = __float2bfloat16(acc[2 * q + 1] * invc);
    out[q] = (uint)(*(unsigned short*)&lo) | ((uint)(*(unsigned short*)&hi) << 16);
  }
  *(uint4*)(agg + (size_t)node * HID + lane * 8) = make_uint4(out[0], out[1], out[2], out[3]);
}

// ------------------------- MFMA GEMM, fused epilogue -------------------------
// out[i, col] = sum_k A1[i,k]*B1[col,k] (+ A2[i,k]*B2[col,k]) + bias[col]
// A*/B*/out bf16 (A row stride = KTOT, out stride = HID), fp32 MFMA accum.
// EPI 0: row-L2-norm -> BN -> ELU.  EPI 1: BN -> ReLU.
// FINAL: instead of storing the 384-wide result, compute the 3-wide final
// projection (W3 fp32, b3) from the LDS-packed result and write out3.
// 256 thr = 4 waves; tile 64 rows x 384 cols x BK=64.
// Staging pipeline: load chunk c+1 into VGPRs while MFMA runs on chunk c
// (regs are free after the ds_write barrier) — global/compute overlap that
// r5's global_load_lds could not express.
// Epilogue: pack bf16 results to LDS (row stride 392), coalesced dwordx4 out.
// In-place safe (out == A1 or A2): block reads only its own 64 rows.
template <int KTOT, bool DUAL, int EPI, bool FINAL>
__global__ __launch_bounds__(256, 2) void mfma_gemm_k(
    const __hip_bfloat16* __restrict__ A1, const __hip_bfloat16* __restrict__ B1,
    const __hip_bfloat16* __restrict__ A2, const __hip_bfloat16* __restrict__ B2,
    const float* __restrict__ bias,
    const float* __restrict__ bng, const float* __restrict__ bnb,
    const float* __restrict__ bnm, const float* __restrict__ bnv,
    __hip_bfloat16* __restrict__ out,
    const float* __restrict__ W3, const float* __restrict__ b3,
    float* __restrict__ out3) {
  __shared__ alignas(16) short smem[64 * 64 + HID * 64];  // 56 KB
  short* sA = smem;
  short* sB = smem + 64 * 64;

  const int t = threadIdx.x;
  const int lane = t & 63;
  const int wv = t >> 6;
  const int n16 = lane & 15;
  const int quad = lane >> 4;
  const int row0 = blockIdx.x * 64;

  floatx4 acc[4][6];
  #pragma unroll
  for (int rt = 0; rt < 4; ++rt)
    #pragma unroll
    for (int ct = 0; ct < 6; ++ct) acc[rt][ct] = (floatx4)0.f;

  constexpr int KCH = KTOT / 64;
  constexpr int NCH = DUAL ? 2 * KCH : KCH;

  uint4 a_reg[2], b_reg[12];
  auto load_chunk = [&](int c) {
    const __hip_bfloat16* Ap;
    const __hip_bfloat16* Bp;
    int kc;
    if (!DUAL || c < KCH) { Ap = A1; Bp = B1; kc = c * 64; }
    else                  { Ap = A2; Bp = B2; kc = (c - KCH) * 64; }
    #pragma unroll
    for (int it = 0; it < 2; ++it) {
      int e = t + it * 256;
      int row = e >> 3, g = e & 7;
      int grow = min(row0 + row, N_NODES - 1);  // clamp ragged last block
      a_reg[it] = *(const uint4*)(Ap + (size_t)grow * KTOT + kc + g * 8);
    }
    #pragma unroll
    for (int it = 0; it < 12; ++it) {
      int e = t + it * 256;
      int col = e >> 3, g = e & 7;
      b_reg[it] = *(const uint4*)(Bp + (size_t)col * KTOT + kc + g * 8);
    }
  };

  load_chunk(0);
  for (int c = 0; c < NCH; ++c) {
    // commit prefetched regs to LDS (XOR-swizzled for conflict-free ds_read)
    #pragma unroll
    for (int it = 0; it < 2; ++it) {
      int e = t + it * 256;
      int row = e >> 3, g = e & 7;
      *(uint4*)&sA[row * 64 + ((g ^ (row & 7)) * 8)] = a_reg[it];
    }
    #pragma unroll
    for (int it = 0; it < 12; ++it) {
      int e = t + it * 256;
      int col = e >> 3, g = e & 7;
      *(uint4*)&sB[col * 64 + ((g ^ (col & 7)) * 8)] = b_reg[it];
    }
    __syncthreads();
    if (c + 1 < NCH) load_chunk(c + 1);  // overlaps the MFMA block below
    #pragma unroll
    for (int kh = 0; kh < 2; ++kh) {
      short8 af[4], bf[6];
      int g = kh * 4 + quad;
      #pragma unroll
      for (int rt = 0; rt < 4; ++rt) {
        int r = rt * 16 + n16;
        af[rt] = *(const short8*)&sA[r * 64 + ((g ^ (r & 7)) * 8)];
      }
      #pragma unroll
      for (int ct = 0; ct < 6; ++ct) {
        int cl = wv * 96 + ct * 16 + n16;
        bf[ct] = *(const short8*)&sB[cl * 64 + ((g ^ (cl & 7)) * 8)];
      }
      #pragma unroll
      for (int rt = 0; rt < 4; ++rt)
        #pragma unroll
        for (int ct = 0; ct < 6; ++ct)
          acc[rt][ct] = __builtin_amdgcn_mfma_f32_16x16x32_bf16(af[rt], bf[ct], acc[rt][ct], 0, 0, 0);
    }
    __syncthreads();
  }

  // ---- epilogue ----
  int gc[6];
  #pragma unroll
  for (int ct = 0; ct < 6; ++ct) {
    gc[ct] = wv * 96 + ct * 16 + n16;
    float bs = bias[gc[ct]];
    #pragma unroll
    for (int rt = 0; rt < 4; ++rt)
      #pragma unroll
      for (int rg = 0; rg < 4; ++rg) acc[rt][ct][rg] += bs;
  }

  if constexpr (EPI == 0) {
    // row L2 norm: 16-lane shfl reduce, then cross-wave via LDS (sA region)
    float* red = (float*)sA;
    float inv[4][4];
    #pragma unroll
    for (int rt = 0; rt < 4; ++rt)
      #pragma unroll
      for (int rg = 0; rg < 4; ++rg) {
        float s = 0.f;
        #pragma unroll
        for (int ct = 0; ct < 6; ++ct) s += acc[rt][ct][rg] * acc[rt][ct][rg];
        #pragma unroll
        for (int off = 1; off < 16; off <<= 1) s += __shfl_xor(s, off);
        if (n16 == 0) red[wv * 64 + rt * 16 + quad * 4 + rg] = s;
      }
    __syncthreads();
    #pragma unroll
    for (int rt = 0; rt < 4; ++rt)
      #pragma unroll
      for (int rg = 0; rg < 4; ++rg) {
        int rl = rt * 16 + quad * 4 + rg;
        float ss = red[rl] + red[64 + rl] + red[128 + rl] + red[192 + rl];
        inv[rt][rg] = 1.f / fmaxf(sqrtf(ss), 1e-12f);
      }
    #pragma unroll
    for (int rt = 0; rt < 4; ++rt)
      #pragma unroll
      for (int ct = 0; ct < 6; ++ct)
        #pragma unroll
        for (int rg = 0; rg < 4; ++rg) acc[rt][ct][rg] *= inv[rt][rg];
    __syncthreads();  // red reads done before smem reused as sO
  }

  // BN + activation, pack bf16 into LDS (row stride 392 shorts)
  constexpr int OS = 392;  // 64 * 392 * 2 B = 50176 B <= 56 KB
  short* sO = smem;
  #pragma unroll
  for (int ct = 0; ct < 6; ++ct) {
    int col = gc[ct];
    float sc = bng[col] * rsqrtf(bnv[col] + BN_EPS);
    float sh = bnb[col] - bnm[col] * sc;
    #pragma unroll
    for (int rt = 0; rt < 4; ++rt)
      #pragma unroll
      for (int rg = 0; rg < 4; ++rg) {
        float xv = acc[rt][ct][rg] * sc + sh;
        if constexpr (EPI == 0)
          xv = xv > 0.f ? xv : expm1f(xv);
        else
          xv = fmaxf(xv, 0.f);
        __hip_bfloat16 bv = __float2bfloat16(xv);
        sO[(rt * 16 + quad * 4 + rg) * OS + col] = *(short*)&bv;
      }
  }
  __syncthreads();

  if constexpr (FINAL) {
    // fused 384 -> 3 projection from LDS; thread (row = t&63, o = t>>6), t<192
    if (t < 192) {
      int row = t & 63, o = t >> 6;
      int grow = row0 + row;
      if (grow < N_NODES) {
        float s = 0.f;
        #pragma unroll
        for (int kb = 0; kb < 48; ++kb) {
          short8 hv = *(const short8*)&sO[row * OS + kb * 8];
          #pragma unroll
          for (int j = 0; j < 8; ++j) s += bf16f(hv[j]) * W3[o * HID + kb * 8 + j];
        }
        out3[grow * OUT_DIM + o] = s + b3[o];
      }
    }
  } else {
    // 64 rows x 768 B out; 48 16B-chunks per row; 256 thr x 12 chunks
    #pragma unroll
    for (int it = 0; it < 12; ++it) {
      int e = t + it * 256;
      int row = e / 48, cs = e % 48;
      int grow = row0 + row;
      if (grow < N_NODES) {
        uint4 v = *(const uint4*)&sO[row * OS + cs * 8];
        *(uint4*)(out + (size_t)grow * HID + cs * 8) = v;
      }
    }
  }
}

// ------------------------- launcher -------------------------

extern "C" void kernel_launch(void* const* d_in, const int* in_sizes, int n_in,
                              void* d_out, int out_size, void* d_ws, size_t ws_size,
                              hipStream_t stream) {
  const float* x = (const float*)d_in[0];
  const int* ei = (const int*)d_in[1];
  const int* src = ei;
  const int* dst = ei + N_EDGES;
  const float* W_l0 = (const float*)d_in[2];
  const float* b_l0 = (const float*)d_in[3];
  const float* W_r0 = (const float*)d_in[4];
  const float* W_l = (const float*)d_in[5];
  const float* b_l = (const float*)d_in[6];
  const float* W_r = (const float*)d_in[7];
  const float* bn_g = (const float*)d_in[8];
  const float* bn_b = (const float*)d_in[9];
  const float* bn_m = (const float*)d_in[10];
  const float* bn_v = (const float*)d_in[11];
  const float* Wp0 = (const float*)d_in[12];
  const float* bp0 = (const float*)d_in[13];
  const float* Wp1 = (const float*)d_in[14];
  const float* bp1 = (const float*)d_in[15];
  const float* Wp2 = (const float*)d_in[16];
  const float* bp2 = (const float*)d_in[17];
  const float* pbn_g = (const float*)d_in[18];
  const float* pbn_b = (const float*)d_in[19];
  const float* pbn_m = (const float*)d_in[20];
  const float* pbn_v = (const float*)d_in[21];

  char* ws = (char*)d_ws;
  size_t off = 0;
  auto walloc = [&](size_t bytes) -> void* {
    void* p = ws + off;
    off = (off + bytes + 255) & ~(size_t)255;
    return p;
  };
  __hip_bfloat16* h   = (__hip_bfloat16*)walloc((size_t)N_NODES * HID * 2);  // 76.8 MB
  __hip_bfloat16* agg = (__hip_bfloat16*)walloc((size_t)N_NODES * HID * 2);  // 76.8 MB
  float* agg10 = (float*)agg;  // 4 MB fp32 overlay; agg not used until layer 1
  __hip_bfloat16* X2  = (__hip_bfloat16*)walloc((size_t)N_NODES * 64 * 2);   // 12.8 MB
  __hip_bfloat16* W2  = (__hip_bfloat16*)walloc((size_t)HID * 64 * 2);
  __hip_bfloat16* WlB  = (__hip_bfloat16*)walloc((size_t)(T_LAYERS - 1) * HID * HID * 2);
  __hip_bfloat16* WrB  = (__hip_bfloat16*)walloc((size_t)(T_LAYERS - 1) * HID * HID * 2);
  __hip_bfloat16* Wp0B = (__hip_bfloat16*)walloc((size_t)HID * HID * 2);
  __hip_bfloat16* Wp1B = (__hip_bfloat16*)walloc((size_t)HID * HID * 2);
  int* cnt     = (int*)walloc((size_t)N_NODES * 4);
  int* row_off = (int*)walloc((size_t)(N_NODES + 1) * 4);
  int* cursor  = (int*)walloc((size_t)N_NODES * 4);
  int* csr     = (int*)walloc((size_t)N_EDGES * 4);
  int* bsum    = (int*)walloc(4096);

  hipMemsetAsync(cnt, 0, (size_t)N_NODES * 4, stream);
  hipMemsetAsync(cursor, 0, (size_t)N_NODES * 4, stream);

  // weight prepack
  const int NW = (T_LAYERS - 1) * HID * HID;
  conv_k<<<(NW + 255) / 256, 256, 0, stream>>>(W_l, WlB, NW);
  conv_k<<<(NW + 255) / 256, 256, 0, stream>>>(W_r, WrB, NW);
  conv_k<<<(HID * HID + 255) / 256, 256, 0, stream>>>(Wp0, Wp0B, HID * HID);
  conv_k<<<(HID * HID + 255) / 256, 256, 0, stream>>>(Wp1, Wp1B, HID * HID);
  packw0_k<<<(HID * 64 + 255) / 256, 256, 0, stream>>>(W_l0, W_r0, W2);

  // CSR build
  count_k<<<(N_EDGES + 255) / 256, 256, 0, stream>>>(dst, cnt, N_EDGES);
  int P = (N_NODES + 1 + 1023) / 1024;
  scan_partial_k<<<P, 1024, 0, stream>>>(cnt, bsum, N_NODES);
  scan_small_k<<<1, 1024, 0, stream>>>(bsum, P);
  scan_final_k<<<P, 1024, 0, stream>>>(cnt, bsum, row_off, N_NODES);
  fill_k<<<(N_EDGES + 255) / 256, 256, 0, stream>>>(src, dst, row_off, cursor, csr, N_EDGES);

  const int GB = (N_NODES + 63) / 64;  // 1563 row-blocks

  // layer 0: agg10 -> pack -> MFMA GEMM (K=64: [x|agg10|pad] x [Wr0|Wl0|pad])
  agg10_k<<<(N_NODES + 7) / 8, 256, 0, stream>>>(x, row_off, csr, agg10, N_NODES);
  pack0_k<<<(N_NODES * 64 + 255) / 256, 256, 0, stream>>>(x, agg10, X2, N_NODES);
  mfma_gemm_k<64, false, 0, false><<<GB, 256, 0, stream>>>(
      X2, W2, nullptr, nullptr, b_l0, bn_g, bn_b, bn_m, bn_v, h,
      nullptr, nullptr, nullptr);

  // layers 1..4 (dual MFMA GEMM, in-place h update)
  for (int t = 1; t < T_LAYERS; ++t) {
    aggv_k<<<(N_NODES + 3) / 4, 256, 0, stream>>>(h, row_off, csr, agg, N_NODES);
    mfma_gemm_k<HID, true, 0, false><<<GB, 256, 0, stream>>>(
        agg, WlB + (size_t)(t - 1) * HID * HID,
        h,   WrB + (size_t)(t - 1) * HID * HID,
        b_l + (size_t)(t - 1) * HID,
        bn_g + (size_t)t * HID, bn_b + (size_t)t * HID,
        bn_m + (size_t)t * HID, bn_v + (size_t)t * HID,
        h, nullptr, nullptr, nullptr);
  }

  // projection MLP: proj0 in-place on h; proj1 fused with the 384->3 output
  mfma_gemm_k<HID, false, 1, false><<<GB, 256, 0, stream>>>(
      h, Wp0B, nullptr, nullptr, bp0, pbn_g, pbn_b, pbn_m, pbn_v, h,
      nullptr, nullptr, nullptr);
  mfma_gemm_k<HID, false, 1, true><<<GB, 256, 0, stream>>>(
      h, Wp1B, nullptr, nullptr, bp1, pbn_g + HID, pbn_b + HID, pbn_m + HID, pbn_v + HID, h,
      Wp2, bp2, (float*)d_out);
}

// Round 7
// 1116.292 us; speedup vs baseline: 1.9149x; 1.9149x over previous
//
#include <hip/hip_runtime.h>
#include <hip/hip_bf16.h>

#define N_NODES 100000
#define N_EDGES 300000
#define IN_DIM 10
#define HID 384
#define OUT_DIM 3
#define T_LAYERS 5
#define BN_EPS 1e-5f

typedef __attribute__((ext_vector_type(8))) short short8;
typedef __attribute__((ext_vector_type(4))) float floatx4;

__device__ __forceinline__ float bf16f(short v) {
  return __uint_as_float(((unsigned)(unsigned short)v) << 16);
}

// ------------------------- CSR build -------------------------

__global__ void count_k(const int* __restrict__ dst, int* __restrict__ cnt, int E) {
  int e = blockIdx.x * blockDim.x + threadIdx.x;
  if (e < E) atomicAdd(&cnt[dst[e]], 1);
}

__global__ void scan_partial_k(const int* __restrict__ cnt, int* __restrict__ bsum, int n) {
  int t = threadIdx.x;
  int i = blockIdx.x * 1024 + t;
  int v = (i < n) ? cnt[i] : 0;
  #pragma unroll
  for (int off = 1; off < 64; off <<= 1) v += __shfl_xor(v, off);
  __shared__ int ws[16];
  if ((t & 63) == 0) ws[t >> 6] = v;
  __syncthreads();
  if (t == 0) {
    int s = 0;
    #pragma unroll
    for (int w = 0; w < 16; ++w) s += ws[w];
    bsum[blockIdx.x] = s;
  }
}

__global__ void scan_small_k(int* __restrict__ bsum, int P) {
  __shared__ int s[1024];
  int t = threadIdx.x;
  int v = (t < P) ? bsum[t] : 0;
  s[t] = v;
  __syncthreads();
  for (int off = 1; off < 1024; off <<= 1) {
    int add = (t >= off) ? s[t - off] : 0;
    __syncthreads();
    s[t] += add;
    __syncthreads();
  }
  if (t < P) bsum[t] = s[t] - v;  // exclusive block-prefix
}

__global__ void scan_final_k(const int* __restrict__ cnt, const int* __restrict__ bsum,
                             int* __restrict__ row_off, int n) {
  int t = threadIdx.x, lane = t & 63, wv = t >> 6;
  int i = blockIdx.x * 1024 + t;
  int v = (i < n) ? cnt[i] : 0;
  int x = v;
  #pragma unroll
  for (int off = 1; off < 64; off <<= 1) {
    int y = __shfl_up(x, off);
    if (lane >= off) x += y;
  }
  __shared__ int ws[16];
  if (lane == 63) ws[wv] = x;
  __syncthreads();
  if (t == 0) {
    int a = 0;
    #pragma unroll
    for (int w = 0; w < 16; ++w) { int tmp = ws[w]; ws[w] = a; a += tmp; }
  }
  __syncthreads();
  int excl = (x - v) + ws[wv] + bsum[blockIdx.x];
  if (i <= n) row_off[i] = excl;
}

__global__ void fill_k(const int* __restrict__ src, const int* __restrict__ dst,
                       const int* __restrict__ row_off, int* __restrict__ cursor,
                       int* __restrict__ csr, int E) {
  int e = blockIdx.x * blockDim.x + threadIdx.x;
  if (e < E) {
    int d = dst[e];
    int pos = atomicAdd(&cursor[d], 1);
    csr[row_off[d] + pos] = src[e];
  }
}

// ------------------------- prepack kernels -------------------------

__global__ void conv_k(const float* __restrict__ src, __hip_bfloat16* __restrict__ dst, int n) {
  int i = blockIdx.x * blockDim.x + threadIdx.x;
  if (i < n) dst[i] = __float2bfloat16(src[i]);
}

// X2[n][64] = { x[n][0..10) , agg10[n][0..10) , 0 pad }
__global__ void pack0_k(const float* __restrict__ x, const float* __restrict__ agg10,
                        __hip_bfloat16* __restrict__ X2, int n) {
  int i = blockIdx.x * blockDim.x + threadIdx.x;
  if (i < n * 64) {
    int node = i >> 6, k = i & 63;
    float v = (k < IN_DIM) ? x[node * IN_DIM + k]
              : (k < 2 * IN_DIM) ? agg10[node * IN_DIM + (k - IN_DIM)] : 0.f;
    X2[i] = __float2bfloat16(v);
  }
}

// W2[o][64] = { W_r0 (pairs x) , W_l0 (pairs agg10) , 0 pad }
__global__ void packw0_k(const float* __restrict__ Wl, const float* __restrict__ Wr,
                         __hip_bfloat16* __restrict__ W2) {
  int i = blockIdx.x * blockDim.x + threadIdx.x;
  if (i < HID * 64) {
    int o = i >> 6, k = i & 63;
    float v = (k < IN_DIM) ? Wr[o * IN_DIM + k]
              : (k < 2 * IN_DIM) ? Wl[o * IN_DIM + (k - IN_DIM)]
              : 0.f;
    W2[i] = __float2bfloat16(v);
  }
}

// ------------------------- aggregation -------------------------

__global__ void agg10_k(const float* __restrict__ x, const int* __restrict__ row_off,
                        const int* __restrict__ csr, float* __restrict__ agg10, int n) {
  int sub = threadIdx.x >> 5;
  int lane = threadIdx.x & 31;
  int node = blockIdx.x * 8 + sub;
  if (node >= n) return;
  int s = row_off[node], e = row_off[node + 1];
  if (lane < IN_DIM) {
    float acc = 0.f;
    for (int j = s; j < e; ++j) acc += x[csr[j] * IN_DIM + lane];
    float c = (float)max(e - s, 1);
    agg10[node * IN_DIM + lane] = acc / c;
  }
}

// F=384 mean aggregation: one wave per node, lanes 0..47 hold 8 bf16 cols each.
__global__ __launch_bounds__(256) void aggv_k(const __hip_bfloat16* __restrict__ h,
                                              const int* __restrict__ row_off,
                                              const int* __restrict__ csr,
                                              __hip_bfloat16* __restrict__ agg, int n) {
  int node = blockIdx.x * 4 + (threadIdx.x >> 6);
  if (node >= n) return;
  int lane = threadIdx.x & 63;
  if (lane >= 48) return;
  int s = row_off[node], e = row_off[node + 1];
  float acc[8] = {0.f, 0.f, 0.f, 0.f, 0.f, 0.f, 0.f, 0.f};
  for (int j = s; j < e; ++j) {
    const uint4 v = *(const uint4*)(h + (size_t)csr[j] * HID + lane * 8);
    uint u0 = v.x, u1 = v.y, u2 = v.z, u3 = v.w;
    acc[0] += __uint_as_float(u0 << 16);
    acc[1] += __uint_as_float(u0 & 0xffff0000u);
    acc[2] += __uint_as_float(u1 << 16);
    acc[3] += __uint_as_float(u1 & 0xffff0000u);
    acc[4] += __uint_as_float(u2 << 16);
    acc[5] += __uint_as_float(u2 & 0xffff0000u);
    acc[6] += __uint_as_float(u3 << 16);
    acc[7] += __uint_as_float(u3 & 0xffff0000u);
  }
  float invc = 1.f / (float)max(e - s, 1);
  uint out[4];
  #pragma unroll
  for (int q = 0; q < 4; ++q) {
    __hip_bfloat16 lo = __float2bfloat16(acc[2 * q] * invc);
    __hip_bfloat16 hi = __float2bfloat16(acc[2 * q + 1] * invc);
    out[q] = (uint)(*(unsigned short*)&lo) | ((uint)(*(unsigned short*)&hi) << 16);
  }
  *(uint4*)(agg + (size_t)node * HID + lane * 8) = make_uint4(out[0], out[1], out[2], out[3]);
}

// ------------------------- MFMA GEMM, fused epilogue -------------------------
// out[i, col] = sum_k A1[i,k]*B1[col,k] (+ A2[i,k]*B2[col,k]) + bias[col]
// A*/B*/out bf16 (A row stride = KTOT, out stride = HID), fp32 MFMA accum.
// EPI 0: row-L2-norm -> BN -> ELU.  EPI 1: BN -> ReLU.
// FINAL: compute 384->3 projection (W3,b3 fp32) from the LDS-packed result.
// 256 thr = 4 waves; tile 64 rows x 384 cols x BK=64.
// Staging: direct global->VGPR->LDS per chunk (r4 structure). NOTE (r6
// post-mortem): do NOT hold prefetch registers across the MFMA block —
// 14 uint4 pinned regs spilled to scratch (WRITE_SIZE 75->666 MB, 2x slower).
// The compiler's own scheduling of these loads already overlaps chunks.
// Epilogue: pack bf16 results to LDS (row stride 392), coalesced dwordx4 out
// (r5: WRITE_SIZE at the 75 MB ideal vs 124 MB for scattered 2B stores).
// In-place safe (out == A1 or A2): block reads only its own 64 rows.
template <int KTOT, bool DUAL, int EPI, bool FINAL>
__global__ __launch_bounds__(256, 2) void mfma_gemm_k(
    const __hip_bfloat16* __restrict__ A1, const __hip_bfloat16* __restrict__ B1,
    const __hip_bfloat16* __restrict__ A2, const __hip_bfloat16* __restrict__ B2,
    const float* __restrict__ bias,
    const float* __restrict__ bng, const float* __restrict__ bnb,
    const float* __restrict__ bnm, const float* __restrict__ bnv,
    __hip_bfloat16* __restrict__ out,
    const float* __restrict__ W3, const float* __restrict__ b3,
    float* __restrict__ out3) {
  __shared__ alignas(16) short smem[64 * 64 + HID * 64];  // 56 KB
  short* sA = smem;
  short* sB = smem + 64 * 64;

  const int t = threadIdx.x;
  const int lane = t & 63;
  const int wv = t >> 6;
  const int n16 = lane & 15;
  const int quad = lane >> 4;
  const int row0 = blockIdx.x * 64;

  floatx4 acc[4][6];
  #pragma unroll
  for (int rt = 0; rt < 4; ++rt)
    #pragma unroll
    for (int ct = 0; ct < 6; ++ct) acc[rt][ct] = (floatx4)0.f;

  constexpr int KCH = KTOT / 64;
  constexpr int NCH = DUAL ? 2 * KCH : KCH;
  for (int c = 0; c < NCH; ++c) {
    const __hip_bfloat16* Ap;
    const __hip_bfloat16* Bp;
    int kc;
    if (!DUAL || c < KCH) { Ap = A1; Bp = B1; kc = c * 64; }
    else                  { Ap = A2; Bp = B2; kc = (c - KCH) * 64; }
    // stage A tile: 64 rows x 64 k (2 x 16B per thread)
    #pragma unroll
    for (int it = 0; it < 2; ++it) {
      int e = t + it * 256;
      int row = e >> 3, g = e & 7;
      int grow = min(row0 + row, N_NODES - 1);  // clamp ragged last block
      uint4 v = *(const uint4*)(Ap + (size_t)grow * KTOT + kc + g * 8);
      *(uint4*)&sA[row * 64 + ((g ^ (row & 7)) * 8)] = v;
    }
    // stage B tile: 384 cols x 64 k (12 x 16B per thread)
    #pragma unroll
    for (int it = 0; it < 12; ++it) {
      int e = t + it * 256;
      int col = e >> 3, g = e & 7;
      uint4 v = *(const uint4*)(Bp + (size_t)col * KTOT + kc + g * 8);
      *(uint4*)&sB[col * 64 + ((g ^ (col & 7)) * 8)] = v;
    }
    __syncthreads();
    #pragma unroll
    for (int kh = 0; kh < 2; ++kh) {
      short8 af[4], bf[6];
      int g = kh * 4 + quad;
      #pragma unroll
      for (int rt = 0; rt < 4; ++rt) {
        int r = rt * 16 + n16;
        af[rt] = *(const short8*)&sA[r * 64 + ((g ^ (r & 7)) * 8)];
      }
      #pragma unroll
      for (int ct = 0; ct < 6; ++ct) {
        int cl = wv * 96 + ct * 16 + n16;
        bf[ct] = *(const short8*)&sB[cl * 64 + ((g ^ (cl & 7)) * 8)];
      }
      #pragma unroll
      for (int rt = 0; rt < 4; ++rt)
        #pragma unroll
        for (int ct = 0; ct < 6; ++ct)
          acc[rt][ct] = __builtin_amdgcn_mfma_f32_16x16x32_bf16(af[rt], bf[ct], acc[rt][ct], 0, 0, 0);
    }
    __syncthreads();
  }

  // ---- epilogue ----
  int gc[6];
  #pragma unroll
  for (int ct = 0; ct < 6; ++ct) {
    gc[ct] = wv * 96 + ct * 16 + n16;
    float bs = bias[gc[ct]];
    #pragma unroll
    for (int rt = 0; rt < 4; ++rt)
      #pragma unroll
      for (int rg = 0; rg < 4; ++rg) acc[rt][ct][rg] += bs;
  }

  if constexpr (EPI == 0) {
    // row L2 norm: 16-lane shfl reduce, then cross-wave via LDS (sA region)
    float* red = (float*)sA;
    float inv[4][4];
    #pragma unroll
    for (int rt = 0; rt < 4; ++rt)
      #pragma unroll
      for (int rg = 0; rg < 4; ++rg) {
        float s = 0.f;
        #pragma unroll
        for (int ct = 0; ct < 6; ++ct) s += acc[rt][ct][rg] * acc[rt][ct][rg];
        #pragma unroll
        for (int off = 1; off < 16; off <<= 1) s += __shfl_xor(s, off);
        if (n16 == 0) red[wv * 64 + rt * 16 + quad * 4 + rg] = s;
      }
    __syncthreads();
    #pragma unroll
    for (int rt = 0; rt < 4; ++rt)
      #pragma unroll
      for (int rg = 0; rg < 4; ++rg) {
        int rl = rt * 16 + quad * 4 + rg;
        float ss = red[rl] + red[64 + rl] + red[128 + rl] + red[192 + rl];
        inv[rt][rg] = 1.f / fmaxf(sqrtf(ss), 1e-12f);
      }
    #pragma unroll
    for (int rt = 0; rt < 4; ++rt)
      #pragma unroll
      for (int ct = 0; ct < 6; ++ct)
        #pragma unroll
        for (int rg = 0; rg < 4; ++rg) acc[rt][ct][rg] *= inv[rt][rg];
    __syncthreads();  // red reads done before smem reused as sO
  }

  // BN + activation, pack bf16 into LDS (row stride 392 shorts)
  constexpr int OS = 392;  // 64 * 392 * 2 B = 50176 B <= 56 KB
  short* sO = smem;
  #pragma unroll
  for (int ct = 0; ct < 6; ++ct) {
    int col = gc[ct];
    float sc = bng[col] * rsqrtf(bnv[col] + BN_EPS);
    float sh = bnb[col] - bnm[col] * sc;
    #pragma unroll
    for (int rt = 0; rt < 4; ++rt)
      #pragma unroll
      for (int rg = 0; rg < 4; ++rg) {
        float xv = acc[rt][ct][rg] * sc + sh;
        if constexpr (EPI == 0)
          xv = xv > 0.f ? xv : expm1f(xv);
        else
          xv = fmaxf(xv, 0.f);
        __hip_bfloat16 bv = __float2bfloat16(xv);
        sO[(rt * 16 + quad * 4 + rg) * OS + col] = *(short*)&bv;
      }
  }
  __syncthreads();

  if constexpr (FINAL) {
    // fused 384 -> 3 projection from LDS; thread (row = t&63, o = t>>6), t<192
    if (t < 192) {
      int row = t & 63, o = t >> 6;
      int grow = row0 + row;
      if (grow < N_NODES) {
        float s = 0.f;
        #pragma unroll
        for (int kb = 0; kb < 48; ++kb) {
          short8 hv = *(const short8*)&sO[row * OS + kb * 8];
          #pragma unroll
          for (int j = 0; j < 8; ++j) s += bf16f(hv[j]) * W3[o * HID + kb * 8 + j];
        }
        out3[grow * OUT_DIM + o] = s + b3[o];
      }
    }
  } else {
    // 64 rows x 768 B out; 48 16B-chunks per row; 256 thr x 12 chunks
    #pragma unroll
    for (int it = 0; it < 12; ++it) {
      int e = t + it * 256;
      int row = e / 48, cs = e % 48;
      int grow = row0 + row;
      if (grow < N_NODES) {
        uint4 v = *(const uint4*)&sO[row * OS + cs * 8];
        *(uint4*)(out + (size_t)grow * HID + cs * 8) = v;
      }
    }
  }
}

// ------------------------- launcher -------------------------

extern "C" void kernel_launch(void* const* d_in, const int* in_sizes, int n_in,
                              void* d_out, int out_size, void* d_ws, size_t ws_size,
                              hipStream_t stream) {
  const float* x = (const float*)d_in[0];
  const int* ei = (const int*)d_in[1];
  const int* src = ei;
  const int* dst = ei + N_EDGES;
  const float* W_l0 = (const float*)d_in[2];
  const float* b_l0 = (const float*)d_in[3];
  const float* W_r0 = (const float*)d_in[4];
  const float* W_l = (const float*)d_in[5];
  const float* b_l = (const float*)d_in[6];
  const float* W_r = (const float*)d_in[7];
  const float* bn_g = (const float*)d_in[8];
  const float* bn_b = (const float*)d_in[9];
  const float* bn_m = (const float*)d_in[10];
  const float* bn_v = (const float*)d_in[11];
  const float* Wp0 = (const float*)d_in[12];
  const float* bp0 = (const float*)d_in[13];
  const float* Wp1 = (const float*)d_in[14];
  const float* bp1 = (const float*)d_in[15];
  const float* Wp2 = (const float*)d_in[16];
  const float* bp2 = (const float*)d_in[17];
  const float* pbn_g = (const float*)d_in[18];
  const float* pbn_b = (const float*)d_in[19];
  const float* pbn_m = (const float*)d_in[20];
  const float* pbn_v = (const float*)d_in[21];

  char* ws = (char*)d_ws;
  size_t off = 0;
  auto walloc = [&](size_t bytes) -> void* {
    void* p = ws + off;
    off = (off + bytes + 255) & ~(size_t)255;
    return p;
  };
  __hip_bfloat16* h   = (__hip_bfloat16*)walloc((size_t)N_NODES * HID * 2);  // 76.8 MB
  __hip_bfloat16* agg = (__hip_bfloat16*)walloc((size_t)N_NODES * HID * 2);  // 76.8 MB
  float* agg10 = (float*)agg;  // 4 MB fp32 overlay; agg not used until layer 1
  __hip_bfloat16* X2  = (__hip_bfloat16*)walloc((size_t)N_NODES * 64 * 2);   // 12.8 MB
  __hip_bfloat16* W2  = (__hip_bfloat16*)walloc((size_t)HID * 64 * 2);
  __hip_bfloat16* WlB  = (__hip_bfloat16*)walloc((size_t)(T_LAYERS - 1) * HID * HID * 2);
  __hip_bfloat16* WrB  = (__hip_bfloat16*)walloc((size_t)(T_LAYERS - 1) * HID * HID * 2);
  __hip_bfloat16* Wp0B = (__hip_bfloat16*)walloc((size_t)HID * HID * 2);
  __hip_bfloat16* Wp1B = (__hip_bfloat16*)walloc((size_t)HID * HID * 2);
  int* cnt     = (int*)walloc((size_t)N_NODES * 4);
  int* row_off = (int*)walloc((size_t)(N_NODES + 1) * 4);
  int* cursor  = (int*)walloc((size_t)N_NODES * 4);
  int* csr     = (int*)walloc((size_t)N_EDGES * 4);
  int* bsum    = (int*)walloc(4096);

  hipMemsetAsync(cnt, 0, (size_t)N_NODES * 4, stream);
  hipMemsetAsync(cursor, 0, (size_t)N_NODES * 4, stream);

  // weight prepack
  const int NW = (T_LAYERS - 1) * HID * HID;
  conv_k<<<(NW + 255) / 256, 256, 0, stream>>>(W_l, WlB, NW);
  conv_k<<<(NW + 255) / 256, 256, 0, stream>>>(W_r, WrB, NW);
  conv_k<<<(HID * HID + 255) / 256, 256, 0, stream>>>(Wp0, Wp0B, HID * HID);
  conv_k<<<(HID * HID + 255) / 256, 256, 0, stream>>>(Wp1, Wp1B, HID * HID);
  packw0_k<<<(HID * 64 + 255) / 256, 256, 0, stream>>>(W_l0, W_r0, W2);

  // CSR build
  count_k<<<(N_EDGES + 255) / 256, 256, 0, stream>>>(dst, cnt, N_EDGES);
  int P = (N_NODES + 1 + 1023) / 1024;
  scan_partial_k<<<P, 1024, 0, stream>>>(cnt, bsum, N_NODES);
  scan_small_k<<<1, 1024, 0, stream>>>(bsum, P);
  scan_final_k<<<P, 1024, 0, stream>>>(cnt, bsum, row_off, N_NODES);
  fill_k<<<(N_EDGES + 255) / 256, 256, 0, stream>>>(src, dst, row_off, cursor, csr, N_EDGES);

  const int GB = (N_NODES + 63) / 64;  // 1563 row-blocks

  // layer 0: agg10 -> pack -> MFMA GEMM (K=64: [x|agg10|pad] x [Wr0|Wl0|pad])
  agg10_k<<<(N_NODES + 7) / 8, 256, 0, stream>>>(x, row_off, csr, agg10, N_NODES);
  pack0_k<<<(N_NODES * 64 + 255) / 256, 256, 0, stream>>>(x, agg10, X2, N_NODES);
  mfma_gemm_k<64, false, 0, false><<<GB, 256, 0, stream>>>(
      X2, W2, nullptr, nullptr, b_l0, bn_g, bn_b, bn_m, bn_v, h,
      nullptr, nullptr, nullptr);

  // layers 1..4 (dual MFMA GEMM, in-place h update)
  for (int t = 1; t < T_LAYERS; ++t) {
    aggv_k<<<(N_NODES + 3) / 4, 256, 0, stream>>>(h, row_off, csr, agg, N_NODES);
    mfma_gemm_k<HID, true, 0, false><<<GB, 256, 0, stream>>>(
        agg, WlB + (size_t)(t - 1) * HID * HID,
        h,   WrB + (size_t)(t - 1) * HID * HID,
        b_l + (size_t)(t - 1) * HID,
        bn_g + (size_t)t * HID, bn_b + (size_t)t * HID,
        bn_m + (size_t)t * HID, bn_v + (size_t)t * HID,
        h, nullptr, nullptr, nullptr);
  }

  // projection MLP: proj0 in-place on h; proj1 fused with the 384->3 output
  mfma_gemm_k<HID, false, 1, false><<<GB, 256, 0, stream>>>(
      h, Wp0B, nullptr, nullptr, bp0, pbn_g, pbn_b, pbn_m, pbn_v, h,
      nullptr, nullptr, nullptr);
  mfma_gemm_k<HID, false, 1, true><<<GB, 256, 0, stream>>>(
      h, Wp1B, nullptr, nullptr, bp1, pbn_g + HID, pbn_b + HID, pbn_m + HID, pbn_v + HID, h,
      Wp2, bp2, (float*)d_out);
}